// Round 16
// baseline (513.715 us; speedup 1.0000x reference)
//
#include <hip/hip_runtime.h>
#include <cstdint>

#define NN    1024
#define MM    32
#define NEDGE 32240
#define MROWS 64480   // 2*NEDGE
#define PX    168     // X tile pitch (ushorts)
#define PST   392     // unified stage pitch: 256 (H1n) + 128 (H1e) + 8 pad
#define GRID  512
#define MAGIC 0x13579BDFu

typedef unsigned short ushort_t;

typedef __bf16 bf16x8 __attribute__((ext_vector_type(8)));
typedef float  floatx4 __attribute__((ext_vector_type(4)));

__device__ __forceinline__ float b2f(ushort_t u) {
    union { unsigned int i; float f; } v; v.i = ((unsigned int)u) << 16; return v.f;
}
__device__ __forceinline__ ushort_t f2b(float f) {
    unsigned int u = __builtin_bit_cast(unsigned int, f);
    u = (u + 0x7FFFu + ((u >> 16) & 1u)) >> 16;
    return (ushort_t)u;
}
__device__ __forceinline__ int edge_base(int i) {
    return (i <= MM) ? ((i * (i - 1)) >> 1) : (496 + (i - MM) * MM);
}
__device__ __forceinline__ void edge_ij(int e, int& i, int& j) {
    if (e < 496) {
        i = (int)((1.0f + sqrtf(8.0f * (float)e + 1.0f)) * 0.5f);
        while (((i * (i - 1)) >> 1) > e) --i;
        while (((i * (i + 1)) >> 1) <= e) ++i;
        j = e - ((i * (i - 1)) >> 1);
    } else {
        int q = e - 496;
        i = MM + (q >> 5);
        j = i - MM + (q & 31);
    }
}

// device-scope grid barrier: all GRID blocks must be co-resident (512 = 2/CU by construction).
// Capped spins: on failure produces wrong answer (bench FAIL), not a hang.
__device__ __forceinline__ void grid_barrier(unsigned* cnt, unsigned* flag) {
    __syncthreads();
    if (threadIdx.x == 0) {
        if (flag) {
            unsigned sp = 0;
            while (__hip_atomic_load(flag, __ATOMIC_ACQUIRE, __HIP_MEMORY_SCOPE_AGENT) != MAGIC) {
                __builtin_amdgcn_s_sleep(2);
                if (++sp > 50000000u) break;
            }
        }
        __threadfence();
        __hip_atomic_fetch_add(cnt, 1u, __ATOMIC_ACQ_REL, __HIP_MEMORY_SCOPE_AGENT);
        unsigned sp = 0;
        while (__hip_atomic_load(cnt, __ATOMIC_ACQUIRE, __HIP_MEMORY_SCOPE_AGENT) < (unsigned)GRID) {
            __builtin_amdgcn_s_sleep(2);
            if (++sp > 50000000u) break;
        }
        __threadfence();
    }
    __syncthreads();
}

__global__ __launch_bounds__(512, 4) void k_mono(
        const float* __restrict__ nodes, const float* __restrict__ edges,
        const float* an1, const float* ban1, const float* an2, const float* ban2,
        const float* ln1, const float* bln1, const float* ln2, const float* bln2,
        const float* ae1, const float* bae1, const float* ae2, const float* bae2,
        const float* le1, const float* ble1, const float* le2, const float* ble2,
        unsigned* syncp,
        ushort_t* pan1, ushort_t* pan2, ushort_t* pae1, ushort_t* pae2,
        ushort_t* ple1, ushort_t* ple2, ushort_t* pln1, ushort_t* pln2,
        ushort_t* nodesb, ushort_t* edgesb, int2* ijt,
        ushort_t* hn, ushort_t* he, ushort_t* pn, ushort_t* pre,
        float* out_nodes, float* out_edges) {
    __shared__ alignas(16) unsigned char arena[51200];
    const int tid = threadIdx.x;
    const int bid = blockIdx.x;
    floatx4 zero = {0.f, 0.f, 0.f, 0.f};
    unsigned* flag = syncp;
    unsigned* cnt  = syncp + 1;

    // ---- init sync (block 0) ----
    if (bid == 0 && tid == 0) {
        cnt[0] = 0; cnt[1] = 0; cnt[2] = 0;
        __threadfence();
        __hip_atomic_store(flag, MAGIC, __ATOMIC_RELEASE, __HIP_MEMORY_SCOPE_AGENT);
    }

    // ================= phase 0: pack =================
    if (bid < 152) {
        float (*tile)[33] = (float(*)[33])arena;
        const float* s; ushort_t* d; int K, N, t;
        if (bid < 40)       { s = an1; d = pan1; K = 160; N = 256; t = bid;       }
        else if (bid < 72)  { s = an2; d = pan2; K = 256; N = 128; t = bid - 40;  }
        else if (bid < 84)  { s = ae1; d = pae1; K = 96;  N = 128; t = bid - 72;  }
        else if (bid < 92)  { s = ae2; d = pae2; K = 128; N = 64;  t = bid - 84;  }
        else if (bid < 101) { s = le1; d = ple1; K = 96;  N = 96;  t = bid - 92;  }
        else if (bid < 104) { s = le2; d = ple2; K = 96;  N = 32;  t = bid - 101; }
        else if (bid < 140) { s = ln1; d = pln1; K = 192; N = 192; t = bid - 104; }
        else                { s = ln2; d = pln2; K = 192; N = 64;  t = bid - 140; }
        int ntn = N >> 5;
        int tk = t / ntn, tn = t - tk * ntn;
        int k0 = tk * 32, n0 = tn * 32;
        int tx = tid & 31, ty = tid >> 5;              // ty 0..15
#pragma unroll
        for (int m = 0; m < 2; ++m)
            tile[ty + m * 16][tx] = s[(size_t)(k0 + ty + m * 16) * N + n0 + tx];
        __syncthreads();
#pragma unroll
        for (int m = 0; m < 2; ++m)
            d[(size_t)(n0 + ty + m * 16) * K + k0 + tx] = f2b(tile[tx][ty + m * 16]);
    }
    {
        int idx = bid * 512 + tid;                     // 0..262143
        if (idx < 32768) {
            float4 v = ((const float4*)nodes)[idx];
            uint2 o;
            o.x = (unsigned)f2b(v.x) | ((unsigned)f2b(v.y) << 16);
            o.y = (unsigned)f2b(v.z) | ((unsigned)f2b(v.w) << 16);
            ((uint2*)nodesb)[idx] = o;
        }
        for (int i4 = idx; i4 < 515840; i4 += 262144) {
            float4 v = ((const float4*)edges)[i4];
            uint2 o;
            o.x = (unsigned)f2b(v.x) | ((unsigned)f2b(v.y) << 16);
            o.y = (unsigned)f2b(v.z) | ((unsigned)f2b(v.w) << 16);
            ((uint2*)edgesb)[i4] = o;
        }
        if (idx < NEDGE) { int i, j; edge_ij(idx, i, j); ijt[idx] = make_int2(i, j); }
    }
    grid_barrier(&cnt[0], flag);

    // ================= phase 1: agg (R15 body) =================
    {
        ushort_t* X  = (ushort_t*)arena;               // 10752 B
        ushort_t* H  = (ushort_t*)(arena + 10752);     // 25088 B
        ushort_t* SO = (ushort_t*)(arena + 35840);     // 8704 B
        ushort_t* TO = (ushort_t*)(arena + 44544);     // 4608 B
        const int w = tid >> 6, l = tid & 63, lrow = l & 15, lq = l >> 4;

        for (int mt = bid; mt < 2015; mt += GRID) {
            if (mt != bid) __syncthreads();

            bf16x8 B0[5], B1[5], B2[3];
#pragma unroll
            for (int kt = 0; kt < 5; ++kt) {
                B0[kt] = *(const bf16x8*)(pan1 + (size_t)(16 * w + lrow) * 160 + kt * 32 + lq * 8);
                B1[kt] = *(const bf16x8*)(pan1 + (size_t)(16 * (w + 8) + lrow) * 160 + kt * 32 + lq * 8);
            }
#pragma unroll
            for (int kt = 0; kt < 3; ++kt)
                B2[kt] = *(const bf16x8*)(pae1 + (size_t)(16 * w + lrow) * 96 + kt * 32 + lq * 8);
            float c0 = ban1[16 * w + lrow];
            float c1 = ban1[16 * (w + 8) + lrow];
            float c2 = bae1[16 * w + lrow];

#pragma unroll
            for (int k = 0; k < 4; ++k) {
                int rr = w * 4 + k;
                int r = mt * 32 + rr;
                int off = (r >= NEDGE) ? 1 : 0;
                int2 ij = ijt[r - off * NEDGE];
                int bN = off * NN;
                unsigned* xr = (unsigned*)(X + rr * PX);
                const unsigned* nj = (const unsigned*)(nodesb + (size_t)(bN + ij.y) * 64);
                const unsigned* ni = (const unsigned*)(nodesb + (size_t)(bN + ij.x) * 64);
                const unsigned* eb = (const unsigned*)(edgesb + (size_t)r * 32);
                if (l < 32) { xr[l] = nj[l]; xr[48 + l] = ni[l]; }
                else        xr[l] = eb[l - 32];
            }
            __syncthreads();

#pragma unroll
            for (int s = 0; s < 2; ++s) {
                bf16x8 A[5];
#pragma unroll
                for (int kt = 0; kt < 5; ++kt)
                    A[kt] = *(const bf16x8*)&X[(s * 16 + lrow) * PX + kt * 32 + lq * 8];
                floatx4 a0 = zero, a1 = zero, a2 = zero;
#pragma unroll
                for (int kt = 0; kt < 5; ++kt) {
                    a0 = __builtin_amdgcn_mfma_f32_16x16x32_bf16(A[kt], B0[kt], a0, 0, 0, 0);
                    a1 = __builtin_amdgcn_mfma_f32_16x16x32_bf16(A[kt], B1[kt], a1, 0, 0, 0);
                }
#pragma unroll
                for (int kt = 0; kt < 3; ++kt)
                    a2 = __builtin_amdgcn_mfma_f32_16x16x32_bf16(A[kt], B2[kt], a2, 0, 0, 0);
#pragma unroll
                for (int r_ = 0; r_ < 4; ++r_) {
                    int row = (s * 16 + lq * 4 + r_) * PST;
                    H[row + 16 * w + lrow]       = f2b(fmaxf(a0[r_] + c0, 0.f));
                    H[row + 128 + 16 * w + lrow] = f2b(fmaxf(a1[r_] + c1, 0.f));
                    H[row + 256 + 16 * w + lrow] = f2b(fmaxf(a2[r_] + c2, 0.f));
                }
            }

            bf16x8 D0[8], D1[8], E[4];
            float d0 = 0.f, d1 = 0.f, d2 = 0.f;
            if (w < 4) {
#pragma unroll
                for (int kt = 0; kt < 8; ++kt) {
                    D0[kt] = *(const bf16x8*)(pan2 + (size_t)(16 * w + lrow) * 256 + kt * 32 + lq * 8);
                    D1[kt] = *(const bf16x8*)(pan2 + (size_t)(16 * (w + 4) + lrow) * 256 + kt * 32 + lq * 8);
                }
                d0 = ban2[16 * w + lrow];
                d1 = ban2[16 * (w + 4) + lrow];
            } else {
                int u = w - 4;
#pragma unroll
                for (int kt = 0; kt < 4; ++kt)
                    E[kt] = *(const bf16x8*)(pae2 + (size_t)(16 * u + lrow) * 128 + kt * 32 + lq * 8);
                d2 = bae2[16 * u + lrow];
            }
            __syncthreads();

            if (w < 4) {
#pragma unroll
                for (int s = 0; s < 2; ++s) {
                    floatx4 a0 = zero, a1 = zero;
#pragma unroll
                    for (int kt = 0; kt < 8; ++kt) {
                        bf16x8 a = *(const bf16x8*)&H[(s * 16 + lrow) * PST + kt * 32 + lq * 8];
                        a0 = __builtin_amdgcn_mfma_f32_16x16x32_bf16(a, D0[kt], a0, 0, 0, 0);
                        a1 = __builtin_amdgcn_mfma_f32_16x16x32_bf16(a, D1[kt], a1, 0, 0, 0);
                    }
#pragma unroll
                    for (int r_ = 0; r_ < 4; ++r_) {
                        int row = (s * 16 + lq * 4 + r_) * 136;
                        SO[row + 16 * w + lrow]      = f2b(fmaxf(a0[r_] + d0, 0.f));
                        SO[row + 64 + 16 * w + lrow] = f2b(fmaxf(a1[r_] + d1, 0.f));
                    }
                }
            } else {
                int u = w - 4;
#pragma unroll
                for (int s = 0; s < 2; ++s) {
                    floatx4 a2 = zero;
#pragma unroll
                    for (int kt = 0; kt < 4; ++kt) {
                        bf16x8 a = *(const bf16x8*)&H[(s * 16 + lrow) * PST + 256 + kt * 32 + lq * 8];
                        a2 = __builtin_amdgcn_mfma_f32_16x16x32_bf16(a, E[kt], a2, 0, 0, 0);
                    }
#pragma unroll
                    for (int r_ = 0; r_ < 4; ++r_)
                        TO[(s * 16 + lq * 4 + r_) * 72 + 16 * u + lrow] = f2b(fmaxf(a2[r_] + d2, 0.f));
                }
            }
            __syncthreads();

            {
                int row = tid >> 4, c = tid & 15;
                ((uint4*)(hn + (size_t)(mt * 32 + row) * 128))[c] = *(const uint4*)&SO[row * 136 + c * 8];
                if (tid < 256) {
                    int row2 = tid >> 3, c2 = tid & 7;
                    ((uint4*)(he + (size_t)(mt * 32 + row2) * 64))[c2] = *(const uint4*)&TO[row2 * 72 + c2 * 8];
                }
            }
        }
    }
    grid_barrier(&cnt[1], nullptr);

    // ================= phase 2: mid (two 256-thread halves per block) =================
    {
        const int half = tid >> 8, t5 = tid & 255;
        for (int p = bid; p < 2048; p += GRID) {
            if (p != bid) __syncthreads();
            int item = 2 * p + half;                   // 0..4095; pairs never mix type
            if (item < 2048) {
                int ri = item;
                int b = ri >> 10, i = ri & 1023;
                int t = min(i, MM);
                int base = b * NEDGE + edge_base(i);
                int c = t5 & 63, g = t5 >> 6;
                float s0 = 0.f, s1 = 0.f;
                for (int q = g; q < t; q += 4) {
                    unsigned u = ((const unsigned*)(hn + (size_t)(base + q) * 128))[c];
                    s0 += b2f((ushort_t)(u & 0xffff));
                    s1 += b2f((ushort_t)(u >> 16));
                }
                float* red = (float*)(arena + half * 4096);    // [4][128]
                red[g * 128 + c * 2] = s0; red[g * 128 + c * 2 + 1] = s1;
                __syncthreads();
                if (t5 < 64) {
                    float inv = 1.0f / (float)max(t, 1);
                    float a0 = (red[t5 * 2] + red[128 + t5 * 2] + red[256 + t5 * 2] + red[384 + t5 * 2]) * inv;
                    float a1 = (red[t5 * 2 + 1] + red[128 + t5 * 2 + 1] + red[256 + t5 * 2 + 1] + red[384 + t5 * 2 + 1]) * inv;
                    ((unsigned*)(pn + (size_t)ri * 128))[t5] = (unsigned)f2b(a0) | ((unsigned)f2b(a1) << 16);
                }
            } else {
                int bi = item - 2048;
                int b = bi >> 10, i = bi & 1023;
                int t = min(i, MM);
                int base = b * NEDGE + edge_base(i);
                ushort_t* hw = (ushort_t*)(arena + half * 4096);   // 32*64
                if (t > 0)
                    for (int u = t5; u < t * 8; u += 256)
                        ((uint4*)hw)[u] = ((const uint4*)he)[(size_t)base * 8 + u];
                __syncthreads();
                if (t > 0 && t5 < 64) {
                    float run = 0.f;
                    for (int q = 0; q < t; ++q) {
                        float v = (q == 0) ? 0.f : run / (float)q;
                        pre[(size_t)(base + q) * 64 + t5] = f2b(v);
                        run += b2f(hw[q * 64 + t5]);
                    }
                }
            }
        }
    }
    grid_barrier(&cnt[2], nullptr);

    // ================= phase 3: fin (two 192-of-256-thread halves per block) =================
    {
        const int half = tid >> 8, t8 = tid & 255;
        const int w = t8 >> 6, l = t8 & 63, lrow = l & 15, lq = l >> 4;
        unsigned char* hb = arena + half * 25600;
        ushort_t* LA = (ushort_t*)hb;
        ushort_t* LB = (ushort_t*)(hb + 12800);

        for (int p = bid; p < 1040; p += GRID) {
            if (p != bid) __syncthreads();
            int item = 2 * p + half;                   // 0..2079 (2079 invalid)
            bool act = (t8 < 192) && (item < 2079);
            if (item < 64) {
                int tile = item;
                if (act)
                    for (int u = t8; u < 768; u += 192) {
                        int row = u / 24, c = u - row * 24;
                        int r = tile * 32 + row;
                        const uint4* src = (c < 16) ? ((const uint4*)(pn + (size_t)r * 128) + c)
                                                    : ((const uint4*)(nodesb + (size_t)r * 64) + (c - 16));
                        *(uint4*)&LA[row * 200 + c * 8] = *src;
                    }
                bf16x8 f1[6][4]; float v1[4];
                if (act) {
#pragma unroll
                    for (int kt = 0; kt < 6; ++kt)
#pragma unroll
                        for (int nt = 0; nt < 4; ++nt)
                            f1[kt][nt] = *(const bf16x8*)(pln1 + (size_t)(w * 64 + nt * 16 + lrow) * 192 + kt * 32 + lq * 8);
#pragma unroll
                    for (int nt = 0; nt < 4; ++nt) v1[nt] = bln1[w * 64 + nt * 16 + lrow];
                }
                __syncthreads();
                if (act) {
                    floatx4 acc[2][4];
#pragma unroll
                    for (int s = 0; s < 2; ++s)
#pragma unroll
                        for (int nt = 0; nt < 4; ++nt) acc[s][nt] = zero;
#pragma unroll
                    for (int s = 0; s < 2; ++s)
#pragma unroll
                        for (int kt = 0; kt < 6; ++kt) {
                            bf16x8 a = *(const bf16x8*)&LA[(s * 16 + lrow) * 200 + kt * 32 + lq * 8];
#pragma unroll
                            for (int nt = 0; nt < 4; ++nt)
                                acc[s][nt] = __builtin_amdgcn_mfma_f32_16x16x32_bf16(a, f1[kt][nt], acc[s][nt], 0, 0, 0);
                        }
#pragma unroll
                    for (int s = 0; s < 2; ++s)
#pragma unroll
                        for (int nt = 0; nt < 4; ++nt) {
                            int col = w * 64 + nt * 16 + lrow;
#pragma unroll
                            for (int r_ = 0; r_ < 4; ++r_)
                                LB[(s * 16 + lq * 4 + r_) * 200 + col] = f2b(fmaxf(acc[s][nt][r_] + v1[nt], 0.f));
                        }
                }
                bf16x8 f2[6][2]; float v2[2] = {0.f, 0.f};
                if (act && w < 2) {
#pragma unroll
                    for (int kt = 0; kt < 6; ++kt)
#pragma unroll
                        for (int nt = 0; nt < 2; ++nt)
                            f2[kt][nt] = *(const bf16x8*)(pln2 + (size_t)(w * 32 + nt * 16 + lrow) * 192 + kt * 32 + lq * 8);
#pragma unroll
                    for (int nt = 0; nt < 2; ++nt) v2[nt] = bln2[w * 32 + nt * 16 + lrow];
                }
                __syncthreads();
                if (act && w < 2) {
                    floatx4 a2[2][2];
#pragma unroll
                    for (int s = 0; s < 2; ++s) { a2[s][0] = zero; a2[s][1] = zero; }
#pragma unroll
                    for (int s = 0; s < 2; ++s)
#pragma unroll
                        for (int kt = 0; kt < 6; ++kt) {
                            bf16x8 a = *(const bf16x8*)&LB[(s * 16 + lrow) * 200 + kt * 32 + lq * 8];
#pragma unroll
                            for (int nt = 0; nt < 2; ++nt)
                                a2[s][nt] = __builtin_amdgcn_mfma_f32_16x16x32_bf16(a, f2[kt][nt], a2[s][nt], 0, 0, 0);
                        }
#pragma unroll
                    for (int s = 0; s < 2; ++s)
#pragma unroll
                        for (int nt = 0; nt < 2; ++nt) {
                            int col = w * 32 + nt * 16 + lrow;
#pragma unroll
                            for (int r_ = 0; r_ < 4; ++r_)
                                out_nodes[(size_t)(item * 32 + s * 16 + lq * 4 + r_) * 64 + col] =
                                    fmaxf(a2[s][nt][r_] + v2[nt], 0.f);
                        }
                }
            } else {
                int mt = item - 64;                    // may be invalid when !act
                if (act)
                    for (int u = t8; u < 384; u += 192) {
                        int row = u / 12, c = u - row * 12;
                        int r = mt * 32 + row;
                        const uint4* src = (c < 8) ? ((const uint4*)(pre + (size_t)r * 64) + c)
                                                   : ((const uint4*)(edgesb + (size_t)r * 32) + (c - 8));
                        *(uint4*)&LA[row * 104 + c * 8] = *src;
                    }
                bf16x8 fb1[3][2]; float v1[2];
                bf16x8 fb2[3]; float v2 = 0.f;
                if (act) {
#pragma unroll
                    for (int kt = 0; kt < 3; ++kt)
#pragma unroll
                        for (int nt = 0; nt < 2; ++nt)
                            fb1[kt][nt] = *(const bf16x8*)(ple1 + (size_t)(w * 32 + nt * 16 + lrow) * 96 + kt * 32 + lq * 8);
#pragma unroll
                    for (int nt = 0; nt < 2; ++nt) v1[nt] = ble1[w * 32 + nt * 16 + lrow];
                    if (w < 2) {
#pragma unroll
                        for (int kt = 0; kt < 3; ++kt)
                            fb2[kt] = *(const bf16x8*)(ple2 + (size_t)(w * 16 + lrow) * 96 + kt * 32 + lq * 8);
                        v2 = ble2[w * 16 + lrow];
                    }
                }
                __syncthreads();
                if (act) {
                    floatx4 acc[2][2];
#pragma unroll
                    for (int s = 0; s < 2; ++s) { acc[s][0] = zero; acc[s][1] = zero; }
#pragma unroll
                    for (int s = 0; s < 2; ++s)
#pragma unroll
                        for (int kt = 0; kt < 3; ++kt) {
                            bf16x8 a = *(const bf16x8*)&LA[(s * 16 + lrow) * 104 + kt * 32 + lq * 8];
#pragma unroll
                            for (int nt = 0; nt < 2; ++nt)
                                acc[s][nt] = __builtin_amdgcn_mfma_f32_16x16x32_bf16(a, fb1[kt][nt], acc[s][nt], 0, 0, 0);
                        }
#pragma unroll
                    for (int s = 0; s < 2; ++s)
#pragma unroll
                        for (int nt = 0; nt < 2; ++nt) {
                            int col = w * 32 + nt * 16 + lrow;
#pragma unroll
                            for (int r_ = 0; r_ < 4; ++r_)
                                LB[(s * 16 + lq * 4 + r_) * 104 + col] = f2b(fmaxf(acc[s][nt][r_] + v1[nt], 0.f));
                        }
                }
                __syncthreads();
                if (act && w < 2) {
                    floatx4 a2[2] = {zero, zero};
#pragma unroll
                    for (int s = 0; s < 2; ++s)
#pragma unroll
                        for (int kt = 0; kt < 3; ++kt) {
                            bf16x8 a = *(const bf16x8*)&LB[(s * 16 + lrow) * 104 + kt * 32 + lq * 8];
                            a2[s] = __builtin_amdgcn_mfma_f32_16x16x32_bf16(a, fb2[kt], a2[s], 0, 0, 0);
                        }
#pragma unroll
                    for (int s = 0; s < 2; ++s) {
                        int col = w * 16 + lrow;
#pragma unroll
                        for (int r_ = 0; r_ < 4; ++r_)
                            out_edges[(size_t)(mt * 32 + s * 16 + lq * 4 + r_) * 32 + col] = fmaxf(a2[s][r_] + v2, 0.f);
                    }
                }
            }
        }
    }
}

extern "C" void kernel_launch(void* const* d_in, const int* in_sizes, int n_in,
                              void* d_out, int out_size, void* d_ws, size_t ws_size,
                              hipStream_t stream) {
    const float* nodes = (const float*)d_in[0];
    const float* edges = (const float*)d_in[1];
    const float* Wan1 = (const float*)d_in[2];  const float* ban1 = (const float*)d_in[3];
    const float* Wan2 = (const float*)d_in[4];  const float* ban2 = (const float*)d_in[5];
    const float* Wln1 = (const float*)d_in[6];  const float* bln1 = (const float*)d_in[7];
    const float* Wln2 = (const float*)d_in[8];  const float* bln2 = (const float*)d_in[9];
    const float* Wae1 = (const float*)d_in[10]; const float* bae1 = (const float*)d_in[11];
    const float* Wae2 = (const float*)d_in[12]; const float* bae2 = (const float*)d_in[13];
    const float* Wle1 = (const float*)d_in[14]; const float* ble1 = (const float*)d_in[15];
    const float* Wle2 = (const float*)d_in[16]; const float* ble2 = (const float*)d_in[17];

    char* ws = (char*)d_ws;
    size_t o = 0;
    auto alloc = [&](size_t bytes) -> void* {
        void* r = ws + o;
        o += (bytes + 255) & ~(size_t)255;
        return r;
    };
    unsigned* syncp  = (unsigned*)alloc(256);
    ushort_t* hn     = (ushort_t*)alloc((size_t)MROWS * 128 * 2);
    ushort_t* he     = (ushort_t*)alloc((size_t)MROWS * 64 * 2);
    ushort_t* pre    = (ushort_t*)alloc((size_t)MROWS * 64 * 2);
    ushort_t* pn     = (ushort_t*)alloc((size_t)2048 * 128 * 2);
    ushort_t* nodesb = (ushort_t*)alloc((size_t)2 * NN * 64 * 2);
    ushort_t* edgesb = (ushort_t*)alloc((size_t)MROWS * 32 * 2);
    int2*     ijt    = (int2*)alloc((size_t)NEDGE * 8);
    ushort_t* pan1 = (ushort_t*)alloc(160 * 256 * 2);
    ushort_t* pan2 = (ushort_t*)alloc(256 * 128 * 2);
    ushort_t* pae1 = (ushort_t*)alloc(96 * 128 * 2);
    ushort_t* pae2 = (ushort_t*)alloc(128 * 64 * 2);
    ushort_t* ple1 = (ushort_t*)alloc(96 * 96 * 2);
    ushort_t* ple2 = (ushort_t*)alloc(96 * 32 * 2);
    ushort_t* pln1 = (ushort_t*)alloc(192 * 192 * 2);
    ushort_t* pln2 = (ushort_t*)alloc(192 * 64 * 2);

    float* out_nodes = (float*)d_out;
    float* out_edges = (float*)d_out + 2 * NN * 64;

    k_mono<<<GRID, 512, 0, stream>>>(nodes, edges,
                                     Wan1, ban1, Wan2, ban2, Wln1, bln1, Wln2, bln2,
                                     Wae1, bae1, Wae2, bae2, Wle1, ble1, Wle2, ble2,
                                     syncp,
                                     pan1, pan2, pae1, pae2, ple1, ple2, pln1, pln2,
                                     nodesb, edgesb, ijt, hn, he, pn, pre,
                                     out_nodes, out_edges);

    (void)in_sizes; (void)n_in; (void)out_size; (void)ws_size;
}